// Round 18
// baseline (250.384 us; speedup 1.0000x reference)
//
#include <hip/hip_runtime.h>
#include <hip/hip_cooperative_groups.h>

namespace cg = cooperative_groups;

#define IN_FEAT 4096
#define OUT_FEAT 4096
#define RANK 64
#define NROWS 16384
#define BT 512             // threads per block (8 waves)
#define NB 256             // grid blocks (1 per CU, coop-safe)
#define NSUB 4             // sub-slabs per block (16 rows each, 64 rows/block)
#define SROWS 16           // rows per sub-slab
#define KCC 256            // producer K-chunk (f32 elems)
#define XSS 264            // xs inner stride (f16)
#define XPS 72             // xp inner stride (f16)
// fallback kernel params
#define TM 32
#define KC 256
#define WA_STRIDE 264
#define XP_STRIDE 72

typedef _Float16 half_t;
typedef _Float16 f16x4 __attribute__((ext_vector_type(4)));
typedef _Float16 f16x8 __attribute__((ext_vector_type(8)));
typedef float f32x4 __attribute__((ext_vector_type(4)));

// lgkm-only barrier: syncs LDS producer/consumer WITHOUT draining the global
// store queue (compiler's __syncthreads emits vmcnt(0) which serializes the
// write stream -- the r17 lesson).
#define SYNCL() do {                                         \
    __builtin_amdgcn_sched_barrier(0);                       \
    asm volatile("s_waitcnt lgkmcnt(0)" ::: "memory");       \
    __builtin_amdgcn_s_barrier();                            \
    __builtin_amdgcn_sched_barrier(0);                       \
} while (0)

__device__ __forceinline__ f16x4 thr4(float4 v, float s) {
    float a0 = fabsf(v.x), a1 = fabsf(v.y), a2 = fabsf(v.z), a3 = fabsf(v.w);
    float lo1 = fminf(a0, a1), hi1 = fmaxf(a0, a1);
    float lo2 = fminf(a2, a3), hi2 = fmaxf(a2, a3);
    float t = fminf(fmaxf(lo1, lo2), fminf(hi1, hi2));  // 2nd-smallest = 3rd-largest
    f16x4 r;
    r[0] = (half_t)(copysignf(fmaxf(a0 - t, 0.0f), v.x) * s);
    r[1] = (half_t)(copysignf(fmaxf(a1 - t, 0.0f), v.y) * s);
    r[2] = (half_t)(copysignf(fmaxf(a2 - t, 0.0f), v.z) * s);
    r[3] = (half_t)(copysignf(fmaxf(a3 - t, 0.0f), v.w) * s);
    return r;
}

__device__ __forceinline__ f16x4 cvt4(f32x4 v) {
    f16x4 h;
    h[0] = (half_t)v[0]; h[1] = (half_t)v[1];
    h[2] = (half_t)v[2]; h[3] = (half_t)v[3];
    return h;
}

// ============ v4: producer/consumer wave pipeline ===========================
// 256 blocks x 512 threads, 21.5 KB LDS, 1 block/CU.
// Waves 0-3 (producers): phase A of sub-slab s -> xp LDS dbuf.
// Waves 4-7 (consumers): phase B of sub-slab s-1 (16 rows x 4096 cols,
// swapped MFMA, direct f32x4 stores). Reads and writes flow CONCURRENTLY.
// Uniform lattice: (NSUB+1) stages x 17 windows, one lgkm-barrier per window
// executed unconditionally by all 8 waves.
__global__ __launch_bounds__(BT) void coop_v4(
    const float* __restrict__ x, const float* __restrict__ wA,
    const float* __restrict__ wB, const float* __restrict__ bias,
    const float* __restrict__ scaleA, const float* __restrict__ scaleB,
    float* __restrict__ out, half_t* __restrict__ wAT, half_t* __restrict__ wBh)
{
    __shared__ __align__(16) half_t xs[2][SROWS][XSS];    // 16.9 KB x-chunk dbuf
    __shared__ __align__(16) half_t xpl[2][SROWS][XPS];   // 4.6 KB xp dbuf

    int tid = threadIdx.x;
    int bid = blockIdx.x;

    // ---- Phase 0: prep weights (131072 threads == 73728 tasks padded) ------
    {
        int id = bid * BT + tid;
        if (id < 65536) {
            int row = id >> 4;
            int gq  = id & 15;
            float s = scaleB[0];
            f16x4 h = thr4(*(const float4*)(wB + (size_t)row * RANK + gq * 4), s);
            *(f16x4*)(wBh + (size_t)row * RANK + gq * 4) = h;
        } else if (id < 65536 + 8192) {
            int t2 = id - 65536;
            int c4 = t2 & 15;
            int k8 = t2 >> 4;
            float s = scaleA[0];
            f16x8 vc0, vc1, vc2, vc3;
#pragma unroll
            for (int i = 0; i < 8; ++i) {
                float4 v = *(const float4*)(wA + (size_t)(k8 * 8 + i) * RANK + c4 * 4);
                f16x4 h = thr4(v, s);
                vc0[i] = h[0]; vc1[i] = h[1]; vc2[i] = h[2]; vc3[i] = h[3];
            }
            *(f16x8*)(wAT + (size_t)(c4 * 4 + 0) * IN_FEAT + k8 * 8) = vc0;
            *(f16x8*)(wAT + (size_t)(c4 * 4 + 1) * IN_FEAT + k8 * 8) = vc1;
            *(f16x8*)(wAT + (size_t)(c4 * 4 + 2) * IN_FEAT + k8 * 8) = vc2;
            *(f16x8*)(wAT + (size_t)(c4 * 4 + 3) * IN_FEAT + k8 * 8) = vc3;
        }
    }
    cg::this_grid().sync();

    int wave = tid >> 6;
    int lane = tid & 63;
    int l16  = lane & 15;
    int g    = lane >> 4;
    bool prod = wave < 4;
    int rw   = wave & 3;               // role-local wave id
    int rowbase = bid * (NSUB * SROWS);

    // producer roles
    int srow = (tid >> 4) & 15;        // staging row (producers: tid 0..255)
    int sseg = tid & 15;               // staging segment
    const half_t* wcol = wAT + (size_t)(rw * 16 + l16) * IN_FEAT;  // xp-col owner
    // consumer role: col strip [rw*1024, rw*1024+1024)
    int cbase = rw * 1024;

    for (int s = 0; s <= NSUB; ++s) {
        bool pa = prod && (s < NSUB);
        bool ca = (!prod) && (s > 0);

        int prow0 = rowbase + s * SROWS;
        int crow0 = rowbase + (s - 1) * SROWS;
        const float* srcrow = x + (size_t)(prow0 + srow) * IN_FEAT + sseg * 4;

        f32x4 acc = {0, 0, 0, 0};      // producer accumulator
        f16x8 a0, a1;                  // consumer xp fragments

        // ---- window 0: producer stages chunk 0; consumer loads a-frags -----
        if (pa) {
            const f32x4* p = (const f32x4*)(srcrow);
            f32x4 t0 = p[0], t1 = p[16], t2 = p[32], t3 = p[48];
            half_t* dst = &xs[0][srow][sseg * 4];
            *(f16x4*)(dst +   0) = cvt4(t0);
            *(f16x4*)(dst +  64) = cvt4(t1);
            *(f16x4*)(dst + 128) = cvt4(t2);
            *(f16x4*)(dst + 192) = cvt4(t3);
        }
        if (ca) {
            const half_t* xr = &xpl[(s - 1) & 1][l16][0];
            a0 = *(const f16x8*)(xr + 8 * g);
            a1 = *(const f16x8*)(xr + 32 + 8 * g);
        }
        SYNCL();

        // ---- windows 1..16 --------------------------------------------------
        for (int w = 1; w <= 16; ++w) {
            if (pa) {
                int c = w - 1;
                // (1) wAT fragments first (oldest in vmcnt queue)
                f16x8 bfr[8];
#pragma unroll
                for (int j = 0; j < 8; ++j)
                    bfr[j] = *(const f16x8*)(wcol + c * KCC + j * 32 + 8 * g);
                __builtin_amdgcn_sched_barrier(0);
                // (2) x prefetch for chunk c+1
                f32x4 ld0, ld1, ld2, ld3;
                if (c + 1 < 16) {
                    const f32x4* p = (const f32x4*)(srcrow + (c + 1) * KCC);
                    ld0 = p[0]; ld1 = p[16]; ld2 = p[32]; ld3 = p[48];
                }
                __builtin_amdgcn_sched_barrier(0);
                // (3) MFMA on chunk c
                const half_t* ar = &xs[c & 1][l16][0];
#pragma unroll
                for (int j = 0; j < 8; ++j) {
                    f16x8 a = *(const f16x8*)(ar + j * 32 + 8 * g);
                    acc = __builtin_amdgcn_mfma_f32_16x16x32_f16(a, bfr[j], acc, 0, 0, 0);
                }
                // (4) commit chunk c+1
                if (c + 1 < 16) {
                    half_t* dst = &xs[(c + 1) & 1][srow][sseg * 4];
                    *(f16x4*)(dst +   0) = cvt4(ld0);
                    *(f16x4*)(dst +  64) = cvt4(ld1);
                    *(f16x4*)(dst + 128) = cvt4(ld2);
                    *(f16x4*)(dst + 192) = cvt4(ld3);
                }
                // (5) final window: publish xp (D: row m=4g+r, col n=l16)
                if (w == 16) {
#pragma unroll
                    for (int r = 0; r < 4; ++r)
                        xpl[s & 1][4 * g + r][rw * 16 + l16] = (half_t)acc[r];
                }
            }
            if (ca) {
                // 4 col-fragments per window; swapped MFMA D = wB' x xp:
                // lane owns out[row = l16][colf + 4g .. +3]
#pragma unroll
                for (int q = 0; q < 4; ++q) {
                    int colf = cbase + ((w - 1) * 4 + q) * 16;
                    const half_t* wp = wBh + (size_t)(colf + l16) * RANK;
                    f16x8 wf0 = *(const f16x8*)(wp + 8 * g);
                    f16x8 wf1 = *(const f16x8*)(wp + 32 + 8 * g);
                    f32x4 c0 = {0, 0, 0, 0};
                    c0 = __builtin_amdgcn_mfma_f32_16x16x32_f16(wf0, a0, c0, 0, 0, 0);
                    c0 = __builtin_amdgcn_mfma_f32_16x16x32_f16(wf1, a1, c0, 0, 0, 0);
                    f32x4 bv = *(const f32x4*)(bias + colf + 4 * g);
                    c0[0] += bv[0]; c0[1] += bv[1]; c0[2] += bv[2]; c0[3] += bv[3];
                    *(f32x4*)&out[(size_t)(crow0 + l16) * OUT_FEAT + colf + 4 * g] = c0;
                }
            }
            SYNCL();
        }
    }
}

// ================= fallback: zero-ws fused (round-4, passing) ===============
__global__ __launch_bounds__(256) void fused_kernel(
    const float* __restrict__ x, const float* __restrict__ wA,
    const float* __restrict__ wB, const float* __restrict__ bias,
    const float* __restrict__ scaleA, const float* __restrict__ scaleB,
    float* __restrict__ out)
{
    __shared__ __align__(16) half_t wAsT[RANK][WA_STRIDE];
    __shared__ float xp_part[2][TM][XP_STRIDE];
    __shared__ __align__(16) half_t xp[TM][XP_STRIDE];

    int tid  = threadIdx.x;
    int wave = tid >> 6;
    int lane = tid & 63;
    int l16  = lane & 15;
    int g    = lane >> 4;
    int rowbase = blockIdx.x * TM;
    int stripe  = wave & 1;
    int ks      = wave >> 1;

    float sA = scaleA[0];
    float sB = scaleB[0];

    const float* xrow = x + (size_t)(rowbase + stripe * 16 + l16) * IN_FEAT;
    f32x4 acc[4] = {f32x4{0,0,0,0}, f32x4{0,0,0,0}, f32x4{0,0,0,0}, f32x4{0,0,0,0}};

    for (int chunk = 0; chunk < IN_FEAT / KC; ++chunk) {
        int k0 = chunk * KC;
#pragma unroll
        for (int pp = 0; pp < 2; ++pp) {
            int p = tid + pp * 256;
            int q = p & 15;
            int r = p >> 4;
            f16x8 vc0, vc1, vc2, vc3;
#pragma unroll
            for (int i = 0; i < 8; ++i) {
                float4 v = *(const float4*)(wA + (size_t)(k0 + 8 * r + i) * RANK + 4 * q);
                f16x4 h = thr4(v, sA);
                vc0[i] = h[0]; vc1[i] = h[1]; vc2[i] = h[2]; vc3[i] = h[3];
            }
            *(f16x8*)&wAsT[4 * q + 0][8 * r] = vc0;
            *(f16x8*)&wAsT[4 * q + 1][8 * r] = vc1;
            *(f16x8*)&wAsT[4 * q + 2][8 * r] = vc2;
            *(f16x8*)&wAsT[4 * q + 3][8 * r] = vc3;
        }
        __syncthreads();

#pragma unroll
        for (int it = 0; it < 4; ++it) {
            int kloc = ks * 128 + it * 32;
            float4 xa = *(const float4*)(xrow + k0 + kloc + 8 * g);
            float4 xb = *(const float4*)(xrow + k0 + kloc + 8 * g + 4);
            f16x8 a;
            a[0] = (half_t)xa.x; a[1] = (half_t)xa.y; a[2] = (half_t)xa.z; a[3] = (half_t)xa.w;
            a[4] = (half_t)xb.x; a[5] = (half_t)xb.y; a[6] = (half_t)xb.z; a[7] = (half_t)xb.w;
#pragma unroll
            for (int f = 0; f < 4; ++f) {
                f16x8 b = *(const f16x8*)&wAsT[16 * f + l16][kloc + 8 * g];
                acc[f] = __builtin_amdgcn_mfma_f32_16x16x32_f16(a, b, acc[f], 0, 0, 0);
            }
        }
        __syncthreads();
    }

#pragma unroll
    for (int f = 0; f < 4; ++f)
#pragma unroll
        for (int r = 0; r < 4; ++r)
            xp_part[ks][stripe * 16 + 4 * g + r][16 * f + l16] = acc[f][r];
    __syncthreads();

#pragma unroll
    for (int i = 0; i < (TM * RANK) / 256; ++i) {
        int e = i * 256 + tid;
        int r = e >> 6, c = e & 63;
        xp[r][c] = (half_t)(xp_part[0][r][c] + xp_part[1][r][c]);
    }
    __syncthreads();

    {
        const half_t* xprow = &xp[stripe * 16 + l16][0];
        f16x8 a0 = *(const f16x8*)(xprow + 8 * g);
        f16x8 a1 = *(const f16x8*)(xprow + 32 + 8 * g);

        int cb0 = ks * (OUT_FEAT / 2);
        for (int cb = cb0; cb < cb0 + OUT_FEAT / 2; cb += 16) {
            int col = cb + l16;
            const float* wp = wB + (size_t)col * RANK;
            float4 w00 = *(const float4*)(wp + 8 * g);
            float4 w01 = *(const float4*)(wp + 8 * g + 4);
            float4 w10 = *(const float4*)(wp + 32 + 8 * g);
            float4 w11 = *(const float4*)(wp + 32 + 8 * g + 4);
            f16x4 b00 = thr4(w00, sB), b01 = thr4(w01, sB);
            f16x4 b10 = thr4(w10, sB), b11 = thr4(w11, sB);
            f16x8 b0, b1;
            b0[0]=b00[0]; b0[1]=b00[1]; b0[2]=b00[2]; b0[3]=b00[3];
            b0[4]=b01[0]; b0[5]=b01[1]; b0[6]=b01[2]; b0[7]=b01[3];
            b1[0]=b10[0]; b1[1]=b10[1]; b1[2]=b10[2]; b1[3]=b10[3];
            b1[4]=b11[0]; b1[5]=b11[1]; b1[6]=b11[2]; b1[7]=b11[3];

            f32x4 acc2 = {0, 0, 0, 0};
            acc2 = __builtin_amdgcn_mfma_f32_16x16x32_f16(a0, b0, acc2, 0, 0, 0);
            acc2 = __builtin_amdgcn_mfma_f32_16x16x32_f16(a1, b1, acc2, 0, 0, 0);
            float bv = bias[col];
#pragma unroll
            for (int r = 0; r < 4; ++r)
                out[(size_t)(rowbase + stripe * 16 + 4 * g + r) * OUT_FEAT + col] = acc2[r] + bv;
        }
    }
}

extern "C" void kernel_launch(void* const* d_in, const int* in_sizes, int n_in,
                              void* d_out, int out_size, void* d_ws, size_t ws_size,
                              hipStream_t stream) {
    const float* x      = (const float*)d_in[0];
    const float* wA     = (const float*)d_in[1];
    const float* wB     = (const float*)d_in[2];
    const float* bias   = (const float*)d_in[3];
    const float* scaleA = (const float*)d_in[4];
    const float* scaleB = (const float*)d_in[5];
    float* out = (float*)d_out;

    const size_t WS_V4 = (size_t)RANK * IN_FEAT * 2        // wAT 512 KB
                       + (size_t)OUT_FEAT * RANK * 2;      // wBh 512 KB

    bool launched = false;
    if (ws_size >= WS_V4 && d_ws != nullptr) {
        half_t* wAT = (half_t*)d_ws;
        half_t* wBh = wAT + (size_t)RANK * IN_FEAT;
        void* args[] = {(void*)&x, (void*)&wA, (void*)&wB, (void*)&bias,
                        (void*)&scaleA, (void*)&scaleB, (void*)&out,
                        (void*)&wAT, (void*)&wBh};
        hipError_t err = hipLaunchCooperativeKernel((void*)coop_v4,
                                                    dim3(NB), dim3(BT),
                                                    args, 0, stream);
        launched = (err == hipSuccess);
    }
    if (!launched) {
        fused_kernel<<<NROWS / TM, 256, 0, stream>>>(x, wA, wB, bias, scaleA, scaleB, out);
    }
}

// Round 19
// 226.259 us; speedup vs baseline: 1.1066x; 1.1066x over previous
//
#include <hip/hip_runtime.h>
#include <hip/hip_cooperative_groups.h>

namespace cg = cooperative_groups;

#define IN_FEAT 4096
#define OUT_FEAT 4096
#define RANK 64
#define NROWS 16384
#define TM 32              // phase-A rows per sub-tile
#define BT 1024            // threads per block (16 waves)
#define NB 256             // grid blocks (1 per CU, coop-safe)
#define KC2 256            // phase-A K-chunk (f32 elems)
#define SXS 264            // xs inner stride (f16)
#define BR 256             // phase-B tile rows (slab)
#define BC 256             // phase-B tile cols
#define BS 72              // phase-B LDS inner stride (f16)
#define KC 256             // fallback kernel chunk
#define WA_STRIDE 264
#define XP_STRIDE 72

typedef _Float16 half_t;
typedef _Float16 f16x4 __attribute__((ext_vector_type(4)));
typedef _Float16 f16x8 __attribute__((ext_vector_type(8)));
typedef float f32x4 __attribute__((ext_vector_type(4)));

__device__ __forceinline__ f16x4 thr4(float4 v, float s) {
    float a0 = fabsf(v.x), a1 = fabsf(v.y), a2 = fabsf(v.z), a3 = fabsf(v.w);
    float lo1 = fminf(a0, a1), hi1 = fmaxf(a0, a1);
    float lo2 = fminf(a2, a3), hi2 = fmaxf(a2, a3);
    float t = fminf(fmaxf(lo1, lo2), fminf(hi1, hi2));  // 2nd-smallest = 3rd-largest
    f16x4 r;
    r[0] = (half_t)(copysignf(fmaxf(a0 - t, 0.0f), v.x) * s);
    r[1] = (half_t)(copysignf(fmaxf(a1 - t, 0.0f), v.y) * s);
    r[2] = (half_t)(copysignf(fmaxf(a2 - t, 0.0f), v.z) * s);
    r[3] = (half_t)(copysignf(fmaxf(a3 - t, 0.0f), v.w) * s);
    return r;
}

__device__ __forceinline__ f16x4 cvt4(f32x4 v) {
    f16x4 h;
    h[0] = (half_t)v[0]; h[1] = (half_t)v[1];
    h[2] = (half_t)v[2]; h[3] = (half_t)v[3];
    return h;
}

// ============ v5: r15 dataflow at 16 waves/CU (BT=1024) =====================
// 256 blocks x 1024 threads, 74.8 KB LDS, 1 block/CU (coop-safe; VGPR<=128
// forced by launch_bounds). Only changed variable vs r15: wave concurrency.
// Phase A: 64 rows/block as 2 concurrent 32-row sub-tiles (8 waves each,
// body identical to the proven r15 phase A). Phase B: r15 fat-tile swapped
// MFMA with 16 waves (each owns 64x64 per tile).
__global__ __launch_bounds__(BT) void coop_v5(
    const float* __restrict__ x, const float* __restrict__ wA,
    const float* __restrict__ wB, const float* __restrict__ bias,
    const float* __restrict__ scaleA, const float* __restrict__ scaleB,
    float* __restrict__ out, half_t* __restrict__ wAT, half_t* __restrict__ wBh,
    half_t* __restrict__ xpw)
{
    __shared__ __align__(16) char pool[BR * BS * 2 + BC * BS * 2]; // 73.7 KB
    __shared__ __align__(16) float biasl[BC];                      // 1 KB

    int tid = threadIdx.x;
    int bid = blockIdx.x;

    // ---- Phase 0: prep weights ----------------------------------------------
    {
        int id = bid * BT + tid;
        if (id < 65536) {
            int row = id >> 4;
            int gq  = id & 15;
            float s = scaleB[0];
            f16x4 h = thr4(*(const float4*)(wB + (size_t)row * RANK + gq * 4), s);
            *(f16x4*)(wBh + (size_t)row * RANK + gq * 4) = h;
        } else if (id < 65536 + 8192) {
            int t2 = id - 65536;
            int c4 = t2 & 15;
            int k8 = t2 >> 4;
            float s = scaleA[0];
            f16x8 vc0, vc1, vc2, vc3;
#pragma unroll
            for (int i = 0; i < 8; ++i) {
                float4 v = *(const float4*)(wA + (size_t)(k8 * 8 + i) * RANK + c4 * 4);
                f16x4 h = thr4(v, s);
                vc0[i] = h[0]; vc1[i] = h[1]; vc2[i] = h[2]; vc3[i] = h[3];
            }
            *(f16x8*)(wAT + (size_t)(c4 * 4 + 0) * IN_FEAT + k8 * 8) = vc0;
            *(f16x8*)(wAT + (size_t)(c4 * 4 + 1) * IN_FEAT + k8 * 8) = vc1;
            *(f16x8*)(wAT + (size_t)(c4 * 4 + 2) * IN_FEAT + k8 * 8) = vc2;
            *(f16x8*)(wAT + (size_t)(c4 * 4 + 3) * IN_FEAT + k8 * 8) = vc3;
        }
    }
    cg::this_grid().sync();

    int wave = tid >> 6;
    int lane = tid & 63;
    int l16  = lane & 15;
    int g    = lane >> 4;

    // ---- Phase A: 64 rows/block = 2 concurrent 32-row sub-tiles -------------
    {
        // xs[sub][buf][32][SXS]
        half_t (*xs)[2][TM][SXS] = (half_t(*)[2][TM][SXS])pool;    // 67.6 KB
        int sub    = wave >> 3;            // which 32-row sub-tile
        int w8     = wave & 7;             // wave-id within sub
        int stripe = w8 & 1;
        int quad   = w8 >> 1;
        int st     = tid & 511;            // thread-id within sub (512 thr/sub)
        int srow   = st >> 4;              // 0..31
        int sseg   = st & 15;              // 0..15
        int rowbase = bid * 64 + sub * TM;
        const float* srcrow = x + (size_t)(rowbase + srow) * IN_FEAT + sseg * 4;

        {   // prologue: stage chunk 0
            const f32x4* p = (const f32x4*)(srcrow);
            f32x4 a0 = p[0], a1 = p[16], a2 = p[32], a3 = p[48];
            half_t* dst = &xs[sub][0][srow][sseg * 4];
            *(f16x4*)(dst +   0) = cvt4(a0);
            *(f16x4*)(dst +  64) = cvt4(a1);
            *(f16x4*)(dst + 128) = cvt4(a2);
            *(f16x4*)(dst + 192) = cvt4(a3);
        }
        __syncthreads();

        f32x4 acc = {0, 0, 0, 0};
        const half_t* wcol = wAT + (size_t)(quad * 16 + l16) * IN_FEAT;
        const half_t* arow = &xs[sub][0][stripe * 16 + l16][0];
        const int xsstep = TM * SXS;
        f32x4 ld0, ld1, ld2, ld3;

        for (int c = 0; c < IN_FEAT / KC2; ++c) {
            // (1) wAT fragments first (oldest in vmcnt queue)
            f16x8 bfr[8];
#pragma unroll
            for (int j = 0; j < 8; ++j)
                bfr[j] = *(const f16x8*)(wcol + c * KC2 + j * 32 + 8 * g);
            __builtin_amdgcn_sched_barrier(0);
            // (2) x prefetch for chunk c+1
            if (c + 1 < IN_FEAT / KC2) {
                const f32x4* p = (const f32x4*)(srcrow + (c + 1) * KC2);
                ld0 = p[0]; ld1 = p[16]; ld2 = p[32]; ld3 = p[48];
            }
            __builtin_amdgcn_sched_barrier(0);

            const half_t* ar = arow + (c & 1) * xsstep;
#pragma unroll
            for (int j = 0; j < 8; ++j) {
                f16x8 a = *(const f16x8*)(ar + j * 32 + 8 * g);
                acc = __builtin_amdgcn_mfma_f32_16x16x32_f16(a, bfr[j], acc, 0, 0, 0);
            }
            if (c + 1 < IN_FEAT / KC2) {
                half_t* dst = &xs[sub][(c + 1) & 1][srow][sseg * 4];
                *(f16x4*)(dst +   0) = cvt4(ld0);
                *(f16x4*)(dst +  64) = cvt4(ld1);
                *(f16x4*)(dst + 128) = cvt4(ld2);
                *(f16x4*)(dst + 192) = cvt4(ld3);
            }
            __syncthreads();
        }

        // C/D: col = lane&15, row = 4*(lane>>4)+reg; full-K f32 -> f16 -> ws
#pragma unroll
        for (int r = 0; r < 4; ++r)
            xpw[(size_t)(rowbase + stripe * 16 + 4 * g + r) * RANK + quad * 16 + l16]
                = (half_t)acc[r];
    }
    cg::this_grid().sync();

    // ---- Phase B: 256-row slab x 4 fat 256-col tiles, 16 waves --------------
    {
        half_t (*xps)[BS] = (half_t(*)[BS])pool;                       // 36 KB
        half_t (*wbs)[BS] = (half_t(*)[BS])(pool + BR * BS * 2);       // 36 KB

        int rb = (bid >> 2) * BR;          // 64 row-slabs, 4 blocks each

        // stage xps once: 256 rows x 64 f16 (32 KB); 1024 thr -> 32 B each
        {
            int row = tid >> 2, q4 = tid & 3;
            const half_t* src = xpw + (size_t)(rb + row) * RANK + q4 * 16;
            f16x8 v0 = *(const f16x8*)(src + 0);
            f16x8 v1 = *(const f16x8*)(src + 8);
            half_t* dst = &xps[row][q4 * 16];
            *(f16x8*)(dst + 0) = v0;
            *(f16x8*)(dst + 8) = v1;
        }

        int wrow = (wave & 3) * 64;        // wave's 64-row quarter
        int wcol = (wave >> 2) * 64;       // wave's 64-col quarter

        for (int t = 0; t < 4; ++t) {
            int cb = ((bid & 3) * 4 + t) * BC;

            // stage wbs: 256 cols x 64 f16 (32 KB) + bias (1 KB)
            {
                int row = tid >> 2, q4 = tid & 3;
                const half_t* src = wBh + (size_t)(cb + row) * RANK + q4 * 16;
                f16x8 v0 = *(const f16x8*)(src + 0);
                f16x8 v1 = *(const f16x8*)(src + 8);
                half_t* dst = &wbs[row][q4 * 16];
                *(f16x8*)(dst + 0) = v0;
                *(f16x8*)(dst + 8) = v1;
                if (tid < BC) biasl[tid] = bias[cb + tid];
            }
            __syncthreads();

            // wb-fragments (MFMA A operand: m = out-col) + bias4, registers
            f16x8 bf0[4], bf1[4];
            f32x4 bv4[4];
#pragma unroll
            for (int ci = 0; ci < 4; ++ci) {
                int c16 = wcol + ci * 16 + l16;
                bf0[ci] = *(const f16x8*)&wbs[c16][8 * g];
                bf1[ci] = *(const f16x8*)&wbs[c16][32 + 8 * g];
                bv4[ci] = *(const f32x4*)&biasl[wcol + ci * 16 + 4 * g];
            }

            // swapped MFMA: D = wbs x xp -> lane owns out[row=l16][4 cols]
            for (int rt = 0; rt < 4; ++rt) {
                const half_t* ar = &xps[wrow + rt * 16 + l16][0];
                f16x8 a0 = *(const f16x8*)(ar + 8 * g);
                f16x8 a1 = *(const f16x8*)(ar + 32 + 8 * g);
                size_t rowoff = (size_t)(rb + wrow + rt * 16 + l16) * OUT_FEAT;
#pragma unroll
                for (int ci = 0; ci < 4; ++ci) {
                    f32x4 acc2 = {0, 0, 0, 0};
                    acc2 = __builtin_amdgcn_mfma_f32_16x16x32_f16(bf0[ci], a0, acc2, 0, 0, 0);
                    acc2 = __builtin_amdgcn_mfma_f32_16x16x32_f16(bf1[ci], a1, acc2, 0, 0, 0);
                    f32x4 st;
                    st[0] = acc2[0] + bv4[ci][0];
                    st[1] = acc2[1] + bv4[ci][1];
                    st[2] = acc2[2] + bv4[ci][2];
                    st[3] = acc2[3] + bv4[ci][3];
                    int col0 = cb + wcol + ci * 16 + 4 * g;
                    *(f32x4*)&out[rowoff + col0] = st;
                }
            }
            __syncthreads();
        }
    }
}

// ================= fallback: zero-ws fused (round-4, passing) ===============
__global__ __launch_bounds__(256) void fused_kernel(
    const float* __restrict__ x, const float* __restrict__ wA,
    const float* __restrict__ wB, const float* __restrict__ bias,
    const float* __restrict__ scaleA, const float* __restrict__ scaleB,
    float* __restrict__ out)
{
    __shared__ __align__(16) half_t wAsT[RANK][WA_STRIDE];
    __shared__ float xp_part[2][TM][XP_STRIDE];
    __shared__ __align__(16) half_t xp[TM][XP_STRIDE];

    int tid  = threadIdx.x;
    int wave = tid >> 6;
    int lane = tid & 63;
    int l16  = lane & 15;
    int g    = lane >> 4;
    int rowbase = blockIdx.x * TM;
    int stripe  = wave & 1;
    int ks      = wave >> 1;

    float sA = scaleA[0];
    float sB = scaleB[0];

    const float* xrow = x + (size_t)(rowbase + stripe * 16 + l16) * IN_FEAT;
    f32x4 acc[4] = {f32x4{0,0,0,0}, f32x4{0,0,0,0}, f32x4{0,0,0,0}, f32x4{0,0,0,0}};

    for (int chunk = 0; chunk < IN_FEAT / KC; ++chunk) {
        int k0 = chunk * KC;
#pragma unroll
        for (int pp = 0; pp < 2; ++pp) {
            int p = tid + pp * 256;
            int q = p & 15;
            int r = p >> 4;
            f16x8 vc0, vc1, vc2, vc3;
#pragma unroll
            for (int i = 0; i < 8; ++i) {
                float4 v = *(const float4*)(wA + (size_t)(k0 + 8 * r + i) * RANK + 4 * q);
                f16x4 h = thr4(v, sA);
                vc0[i] = h[0]; vc1[i] = h[1]; vc2[i] = h[2]; vc3[i] = h[3];
            }
            *(f16x8*)&wAsT[4 * q + 0][8 * r] = vc0;
            *(f16x8*)&wAsT[4 * q + 1][8 * r] = vc1;
            *(f16x8*)&wAsT[4 * q + 2][8 * r] = vc2;
            *(f16x8*)&wAsT[4 * q + 3][8 * r] = vc3;
        }
        __syncthreads();

#pragma unroll
        for (int it = 0; it < 4; ++it) {
            int kloc = ks * 128 + it * 32;
            float4 xa = *(const float4*)(xrow + k0 + kloc + 8 * g);
            float4 xb = *(const float4*)(xrow + k0 + kloc + 8 * g + 4);
            f16x8 a;
            a[0] = (half_t)xa.x; a[1] = (half_t)xa.y; a[2] = (half_t)xa.z; a[3] = (half_t)xa.w;
            a[4] = (half_t)xb.x; a[5] = (half_t)xb.y; a[6] = (half_t)xb.z; a[7] = (half_t)xb.w;
#pragma unroll
            for (int f = 0; f < 4; ++f) {
                f16x8 b = *(const f16x8*)&wAsT[16 * f + l16][kloc + 8 * g];
                acc[f] = __builtin_amdgcn_mfma_f32_16x16x32_f16(a, b, acc[f], 0, 0, 0);
            }
        }
        __syncthreads();
    }

#pragma unroll
    for (int f = 0; f < 4; ++f)
#pragma unroll
        for (int r = 0; r < 4; ++r)
            xp_part[ks][stripe * 16 + 4 * g + r][16 * f + l16] = acc[f][r];
    __syncthreads();

#pragma unroll
    for (int i = 0; i < (TM * RANK) / 256; ++i) {
        int e = i * 256 + tid;
        int r = e >> 6, c = e & 63;
        xp[r][c] = (half_t)(xp_part[0][r][c] + xp_part[1][r][c]);
    }
    __syncthreads();

    {
        const half_t* xprow = &xp[stripe * 16 + l16][0];
        f16x8 a0 = *(const f16x8*)(xprow + 8 * g);
        f16x8 a1 = *(const f16x8*)(xprow + 32 + 8 * g);

        int cb0 = ks * (OUT_FEAT / 2);
        for (int cb = cb0; cb < cb0 + OUT_FEAT / 2; cb += 16) {
            int col = cb + l16;
            const float* wp = wB + (size_t)col * RANK;
            float4 w00 = *(const float4*)(wp + 8 * g);
            float4 w01 = *(const float4*)(wp + 8 * g + 4);
            float4 w10 = *(const float4*)(wp + 32 + 8 * g);
            float4 w11 = *(const float4*)(wp + 32 + 8 * g + 4);
            f16x4 b00 = thr4(w00, sB), b01 = thr4(w01, sB);
            f16x4 b10 = thr4(w10, sB), b11 = thr4(w11, sB);
            f16x8 b0, b1;
            b0[0]=b00[0]; b0[1]=b00[1]; b0[2]=b00[2]; b0[3]=b00[3];
            b0[4]=b01[0]; b0[5]=b01[1]; b0[6]=b01[2]; b0[7]=b01[3];
            b1[0]=b10[0]; b1[1]=b10[1]; b1[2]=b10[2]; b1[3]=b10[3];
            b1[4]=b11[0]; b1[5]=b11[1]; b1[6]=b11[2]; b1[7]=b11[3];

            f32x4 acc2 = {0, 0, 0, 0};
            acc2 = __builtin_amdgcn_mfma_f32_16x16x32_f16(a0, b0, acc2, 0, 0, 0);
            acc2 = __builtin_amdgcn_mfma_f32_16x16x32_f16(a1, b1, acc2, 0, 0, 0);
            float bv = bias[col];
#pragma unroll
            for (int r = 0; r < 4; ++r)
                out[(size_t)(rowbase + stripe * 16 + 4 * g + r) * OUT_FEAT + col] = acc2[r] + bv;
        }
    }
}

extern "C" void kernel_launch(void* const* d_in, const int* in_sizes, int n_in,
                              void* d_out, int out_size, void* d_ws, size_t ws_size,
                              hipStream_t stream) {
    const float* x      = (const float*)d_in[0];
    const float* wA     = (const float*)d_in[1];
    const float* wB     = (const float*)d_in[2];
    const float* bias   = (const float*)d_in[3];
    const float* scaleA = (const float*)d_in[4];
    const float* scaleB = (const float*)d_in[5];
    float* out = (float*)d_out;

    const size_t WS_V5 = (size_t)RANK * IN_FEAT * 2        // wAT   512 KB
                       + (size_t)OUT_FEAT * RANK * 2       // wBh   512 KB
                       + (size_t)NROWS * RANK * 2;         // xpw   2 MB

    bool launched = false;
    if (ws_size >= WS_V5 && d_ws != nullptr) {
        half_t* wAT = (half_t*)d_ws;
        half_t* wBh = wAT + (size_t)RANK * IN_FEAT;
        half_t* xpw = wBh + (size_t)OUT_FEAT * RANK;
        void* args[] = {(void*)&x, (void*)&wA, (void*)&wB, (void*)&bias,
                        (void*)&scaleA, (void*)&scaleB, (void*)&out,
                        (void*)&wAT, (void*)&wBh, (void*)&xpw};
        hipError_t err = hipLaunchCooperativeKernel((void*)coop_v5,
                                                    dim3(NB), dim3(BT),
                                                    args, 0, stream);
        launched = (err == hipSuccess);
    }
    if (!launched) {
        fused_kernel<<<NROWS / TM, 256, 0, stream>>>(x, wA, wB, bias, scaleA, scaleB, out);
    }
}